// Round 1
// baseline (135.639 us; speedup 1.0000x reference)
//
#include <hip/hip_runtime.h>

#define B_ROWS 128
#define T_SAMP 160000
#define NSEC 3

struct Coefs {
  float b0[NSEC], b1[NSEC], b2[NSEC], a1[NSEC], a2[NSEC];
};

__device__ __forceinline__ void load_coefs(const float* __restrict__ sos, Coefs& c) {
#pragma unroll
  for (int s = 0; s < NSEC; ++s) {
    c.b0[s] = sos[s * 6 + 0];
    c.b1[s] = sos[s * 6 + 1];
    c.b2[s] = sos[s * 6 + 2];
    c.a1[s] = sos[s * 6 + 4];
    c.a2[s] = sos[s * 6 + 5];
  }
}

// One DF2T cascade time-step. State layout: z[2*s]=z0_s, z[2*s+1]=z1_s.
// Mirrors the reference exactly (same op order; fmaf for speed, thresh is loose).
__device__ __forceinline__ float df2t_step(const Coefs& c, float z[6], float x) {
  float y = x;
#pragma unroll
  for (int s = 0; s < NSEC; ++s) {
    float out = fmaf(c.b0[s], y, z[2 * s]);
    float t0  = fmaf(c.b1[s], y, z[2 * s + 1]);
    z[2 * s]     = fmaf(-c.a1[s], out, t0);
    float t1  = c.b2[s] * y;
    z[2 * s + 1] = fmaf(-c.a2[s], out, t1);
    y = out;
  }
  return y;
}

// Pass 1: zero-state response of each chunk -> final state f[r][c][6]
__global__ void pass1_kernel(const float* __restrict__ x, const float* __restrict__ sos,
                             float* __restrict__ f, int C, int L) {
  int tid = blockIdx.x * blockDim.x + threadIdx.x;
  if (tid >= B_ROWS * C) return;
  int r = tid / C, cc = tid % C;
  Coefs cf; load_coefs(sos, cf);
  float z[6] = {0.f, 0.f, 0.f, 0.f, 0.f, 0.f};
  const float4* xp = reinterpret_cast<const float4*>(x + (size_t)r * T_SAMP + (size_t)cc * L);
  const int n4 = L >> 2;
  for (int i = 0; i < n4; ++i) {
    float4 v = xp[i];
    df2t_step(cf, z, v.x);
    df2t_step(cf, z, v.y);
    df2t_step(cf, z, v.z);
    df2t_step(cf, z, v.w);
  }
  float* fo = f + (size_t)tid * 6;
#pragma unroll
  for (int k = 0; k < 6; ++k) fo[k] = z[k];
}

// 6x6 matmul, fully unrolled so arrays stay in registers (rule #20).
__device__ __forceinline__ void mat_mul6(float D[36], const float A[36], const float Bm[36]) {
#pragma unroll
  for (int i = 0; i < 6; ++i) {
#pragma unroll
    for (int j = 0; j < 6; ++j) {
      float s = A[i * 6 + 0] * Bm[0 * 6 + j];
#pragma unroll
      for (int k = 1; k < 6; ++k) s = fmaf(A[i * 6 + k], Bm[k * 6 + j], s);
      D[i * 6 + j] = s;
    }
  }
}

// Middle: per-row boundary scan  z[c+1] = A^L z[c] + f[c], emit z_start[r][c][6].
// One block per row; bulk load f row into LDS, lane 0 scans in place, bulk store.
__global__ __launch_bounds__(64) void middle_scan(const float* __restrict__ f,
                                                  const float* __restrict__ sos,
                                                  float* __restrict__ zs, int C, int L) {
  __shared__ float lds[4800];  // C*6 <= 4800 (C <= 800)
  const int r = blockIdx.x;
  const int lane = threadIdx.x;
  const int n = C * 6;
  const int n4 = n >> 2;
  const float4* fp = reinterpret_cast<const float4*>(f + (size_t)r * n);
  float4* lp = reinterpret_cast<float4*>(lds);
  for (int i = lane; i < n4; i += 64) lp[i] = fp[i];
  __syncthreads();

  if (lane == 0) {
    Coefs cf; load_coefs(sos, cf);
    // Build A by stepping unit basis vectors with x=0.
    float A[36];
#pragma unroll
    for (int j = 0; j < 6; ++j) {
      float z[6] = {0.f, 0.f, 0.f, 0.f, 0.f, 0.f};
      z[j] = 1.0f;
      df2t_step(cf, z, 0.0f);
#pragma unroll
      for (int i = 0; i < 6; ++i) A[i * 6 + j] = z[i];
    }
    // M = A^L by repeated squaring (powers commute; ~10 matmuls).
    float M[36], P[36], Tm[36];
#pragma unroll
    for (int i = 0; i < 36; ++i) { M[i] = 0.0f; P[i] = A[i]; }
#pragma unroll
    for (int i = 0; i < 6; ++i) M[i * 6 + i] = 1.0f;
    int e = L;
    while (e) {
      if (e & 1) {
        mat_mul6(Tm, M, P);
#pragma unroll
        for (int i = 0; i < 36; ++i) M[i] = Tm[i];
      }
      e >>= 1;
      if (e) {
        mat_mul6(Tm, P, P);
#pragma unroll
        for (int i = 0; i < 36; ++i) P[i] = Tm[i];
      }
    }
    // In-place exclusive scan over chunks, 1-ahead LDS prefetch to hide latency.
    float z[6] = {0.f, 0.f, 0.f, 0.f, 0.f, 0.f};
    float fc[6];
#pragma unroll
    for (int k = 0; k < 6; ++k) fc[k] = lds[k];
    for (int c = 0; c < C; ++c) {
      float fn[6];
      const int cn = (c + 1 < C) ? (c + 1) : c;
#pragma unroll
      for (int k = 0; k < 6; ++k) fn[k] = lds[cn * 6 + k];
      // z_start[c] = state before chunk c (overwrite f slot, already consumed)
#pragma unroll
      for (int k = 0; k < 6; ++k) lds[c * 6 + k] = z[k];
      float zn[6];
#pragma unroll
      for (int i = 0; i < 6; ++i) {
        float s = fc[i];
#pragma unroll
        for (int k2 = 0; k2 < 6; ++k2) s = fmaf(M[i * 6 + k2], z[k2], s);
        zn[i] = s;
      }
#pragma unroll
      for (int k = 0; k < 6; ++k) { z[k] = zn[k]; fc[k] = fn[k]; }
    }
  }
  __syncthreads();
  float4* zp = reinterpret_cast<float4*>(zs + (size_t)r * n);
  for (int i = lane; i < n4; i += 64) zp[i] = lp[i];
}

// Pass 2: re-run each chunk from its exact starting state, write outputs.
__global__ void pass2_kernel(const float* __restrict__ x, const float* __restrict__ sos,
                             const float* __restrict__ zs, float* __restrict__ y,
                             int C, int L) {
  int tid = blockIdx.x * blockDim.x + threadIdx.x;
  if (tid >= B_ROWS * C) return;
  int r = tid / C, cc = tid % C;
  Coefs cf; load_coefs(sos, cf);
  float z[6];
  const float* zp0 = zs + (size_t)tid * 6;
#pragma unroll
  for (int k = 0; k < 6; ++k) z[k] = zp0[k];
  const size_t base = (size_t)r * T_SAMP + (size_t)cc * L;
  const float4* xp = reinterpret_cast<const float4*>(x + base);
  float4* yp = reinterpret_cast<float4*>(y + base);
  const int n4 = L >> 2;
  for (int i = 0; i < n4; ++i) {
    float4 v = xp[i];
    float4 w;
    w.x = df2t_step(cf, z, v.x);
    w.y = df2t_step(cf, z, v.y);
    w.z = df2t_step(cf, z, v.z);
    w.w = df2t_step(cf, z, v.w);
    yp[i] = w;
  }
}

extern "C" void kernel_launch(void* const* d_in, const int* in_sizes, int n_in,
                              void* d_out, int out_size, void* d_ws, size_t ws_size,
                              hipStream_t stream) {
  const float* x = (const float*)d_in[0];
  const float* sos = (const float*)d_in[1];
  float* y = (float*)d_out;

  // Pick chunk count C (L = T/C, L multiple of 4) based on workspace size.
  int C = 400;
  const int cand[4] = {400, 100, 20, 4};
  for (int i = 0; i < 4; ++i) {
    size_t need = (size_t)2 * B_ROWS * cand[i] * 6 * sizeof(float);
    if (need <= ws_size) { C = cand[i]; break; }
  }
  const int L = T_SAMP / C;

  float* f = (float*)d_ws;                       // [B][C][6] zero-state final states
  float* zst = f + (size_t)B_ROWS * C * 6;       // [B][C][6] exact chunk-start states

  const int threads = B_ROWS * C;
  const int blocks = (threads + 255) / 256;
  hipLaunchKernelGGL(pass1_kernel, dim3(blocks), dim3(256), 0, stream, x, sos, f, C, L);
  hipLaunchKernelGGL(middle_scan, dim3(B_ROWS), dim3(64), 0, stream, f, sos, zst, C, L);
  hipLaunchKernelGGL(pass2_kernel, dim3(blocks), dim3(256), 0, stream, x, sos, zst, y, C, L);
}